// Round 1
// baseline (56.799 us; speedup 1.0000x reference)
//
#include <hip/hip_runtime.h>

// Problem constants (from reference)
constexpr int Bn = 8, Hn = 1536, Wn = 2048;
constexpr int NUM_GTS = 64;
constexpr float INV_N = 1.0f / (float)((long long)Bn * Hn * Wn);

// One thread = 4 consecutive columns of one row, across all 8 batch planes.
// 512 threads per row -> each 64-lane wave lies in a single row, so a single
// __ballot (lane i tests box i's row interval) yields the per-row active-box
// bitmask for the whole wave.
__global__ __launch_bounds__(256) void depth_loss_kernel(
    const float* __restrict__ depth,
    const int*   __restrict__ bbox,
    float*       __restrict__ out)
{
    __shared__ int s_tlx[NUM_GTS], s_tly[NUM_GTS], s_brx[NUM_GTS], s_bry[NUM_GTS];
    const int tid = threadIdx.x;
    if (tid < NUM_GTS) {
        s_tlx[tid] = bbox[tid * 4 + 0];
        s_tly[tid] = bbox[tid * 4 + 1];
        s_brx[tid] = bbox[tid * 4 + 2];
        s_bry[tid] = bbox[tid * 4 + 3];
    }
    __syncthreads();

    const int gid  = blockIdx.x * 256 + tid;     // pixel-group id, [0, 786432)
    const int r    = gid >> 9;                   // / 512 groups per row
    const int c0   = (gid & 511) << 2;           // * 4 columns per group
    const int lane = tid & 63;

    // Row-interval test for box = lane; ballot -> per-row 64-box mask.
    const bool rowhit = (r >= s_tly[lane] - 1) && (r < s_bry[lane]);
    unsigned long long rowm = __ballot(rowhit);

    // Column check only for boxes active in this row (~7 avg).
    unsigned tbits = 0u;
    while (rowm) {
        const int i = __ffsll((long long)rowm) - 1;
        rowm &= rowm - 1;
        int lo = s_tlx[i] - 1 - c0;
        int hi = s_brx[i] - c0;
        lo = lo < 0 ? 0 : lo;
        hi = hi > 4 ? 4 : hi;
        if (lo < hi) tbits |= ((1u << hi) - (1u << lo));
        if (tbits == 0xFu) break;
    }

    // Focal-loss sum over 8 batch planes x 4 columns.
    float acc = 0.0f;
    const long long base = (long long)r * Wn + c0;
    const long long plane = (long long)Hn * Wn;
#pragma unroll
    for (int b = 0; b < Bn; ++b) {
        const float4 v = *reinterpret_cast<const float4*>(depth + base + b * plane);
        const float pv[4] = {v.x, v.y, v.z, v.w};
#pragma unroll
        for (int j = 0; j < 4; ++j) {
            const float p = pv[j];
            float x = 1.0f - 2.0f * p;          // target 0
            if (tbits & (1u << j)) x = -x;      // target 1
            const float e  = __expf(x);
            const float l  = __logf(1.0f + e);  // = -logpt_t  (1+e in [1.37,3.72])
            const float pt = 1.0f / (1.0f + e);
            const float om = 1.0f - pt;
            acc += om * om * l;                 // -(1-pt)^2 * logpt_t
        }
    }

    // Wave reduce (64 lanes), then block reduce, one atomic per block.
#pragma unroll
    for (int off = 32; off > 0; off >>= 1)
        acc += __shfl_down(acc, off, 64);

    __shared__ float s_part[4];
    const int w = tid >> 6;
    if (lane == 0) s_part[w] = acc;
    __syncthreads();
    if (tid == 0) {
        const float s = s_part[0] + s_part[1] + s_part[2] + s_part[3];
        atomicAdd(out, s * INV_N);              // LOSS_WEIGHT = 1
    }
}

extern "C" void kernel_launch(void* const* d_in, const int* in_sizes, int n_in,
                              void* d_out, int out_size, void* d_ws, size_t ws_size,
                              hipStream_t stream) {
    const float* depth = (const float*)d_in[0];
    const int*   bbox  = (const int*)d_in[1];
    float*       out   = (float*)d_out;

    hipMemsetAsync(d_out, 0, sizeof(float), stream);

    const int groups = (Hn * Wn) / 4;           // 786432 pixel groups
    const int blocks = groups / 256;            // 3072
    depth_loss_kernel<<<blocks, 256, 0, stream>>>(depth, bbox, out);
}